// Round 1
// baseline (463.251 us; speedup 1.0000x reference)
//
#include <hip/hip_runtime.h>
#include <stdint.h>

using f32x4  = __attribute__((ext_vector_type(4))) float;
using short8 = __attribute__((ext_vector_type(8))) short;
typedef unsigned short u16;
typedef unsigned int   u32;

// B=8, H=8, L=1024, DM=512, DK=DV=64.  M = B*L = 8192.

static __device__ __forceinline__ u16 f2bf(float f) {
  union { float f; u32 u; } v; v.f = f;
  u32 r = v.u + 0x7fffu + ((v.u >> 16) & 1u);   // RNE
  return (u16)(r >> 16);
}
static __device__ __forceinline__ float bf2f(u16 u) {
  union { u32 u; float f; } v; v.u = ((u32)u) << 16;
  return v.f;
}

// ---------------- fp32 -> bf16 elementwise ----------------
__global__ __launch_bounds__(256) void k_cvt(const float* __restrict__ src,
                                             u16* __restrict__ dst, int n4) {
  int i = blockIdx.x * 256 + threadIdx.x;
  if (i >= n4) return;
  float4 v = ((const float4*)src)[i];
  ushort4 o;
  o.x = f2bf(v.x); o.y = f2bf(v.y); o.z = f2bf(v.z); o.w = f2bf(v.w);
  ((ushort4*)dst)[i] = o;
}

// ---------------- W [512 k][512 n] fp32 -> Wt [n][k] bf16 ----------------
__global__ __launch_bounds__(256) void k_cvt_wt(const float* __restrict__ W,
                                                u16* __restrict__ Wt) {
  __shared__ float t[32][33];
  int tx = threadIdx.x & 31, ty = threadIdx.x >> 5;   // 32 x 8
  int x0 = blockIdx.x * 32, y0 = blockIdx.y * 32;     // x = n, y = k
  #pragma unroll
  for (int i = 0; i < 4; i++)
    t[ty + i*8][tx] = W[(y0 + ty + i*8) * 512 + (x0 + tx)];
  __syncthreads();
  #pragma unroll
  for (int i = 0; i < 4; i++)
    Wt[(x0 + ty + i*8) * 512 + (y0 + tx)] = f2bf(t[tx][ty + i*8]);
}

// ------------- rel embeddings: relk80 [80][64] (zero-pad rows>=65),
//               relvT [64 dv][96 bucket] (zero-pad buckets>=65) -------------
__global__ __launch_bounds__(256) void k_prep_rel(const float* __restrict__ rk,
                                                  const float* __restrict__ rv,
                                                  u16* __restrict__ relk80,
                                                  u16* __restrict__ relvT) {
  int i = blockIdx.x * 256 + threadIdx.x;
  if (i < 80*64) {
    int row = i >> 6;
    relk80[i] = (row < 65) ? f2bf(rk[i]) : (u16)0;
  }
  int j = i - 80*64;
  if (j >= 0 && j < 64*96) {
    int dv = j / 96, bk = j % 96;
    relvT[j] = (bk < 65) ? f2bf(rv[bk*64 + dv]) : (u16)0;
  }
}

// ---------------- bf16 MFMA GEMM: C[8192,512] = X[8192,512] @ Wt^T + bias ---
// Wt is [n][k].  mode 0: fp32 out, plain [m][n] (d_out).
// mode 1: bf16 out at [b,h,l,d] = ((b*8+h)*1024+l)*64+d   (q/k; q uses scale=0.125)
// mode 2: bf16 out at [b,h,d,l] = ((b*8+h)*64+d)*1024+l   (v transposed)
__global__ __launch_bounds__(256) void k_gemm(const u16* __restrict__ X,
                                              const u16* __restrict__ Wt,
                                              const float* __restrict__ bias,
                                              void* __restrict__ outp,
                                              int mode, float scale) {
  __shared__ u16 As[128*32];   // [m][k] rows of 64B
  __shared__ u16 Bs[128*32];   // [n][k]
  int tid = threadIdx.x;
  int lane = tid & 63, wv = tid >> 6;
  int quad = lane >> 4, l15 = lane & 15;
  int n0 = blockIdx.x * 128, m0 = blockIdx.y * 128;
  int wm = (wv >> 1) * 64, wn = (wv & 1) * 64;
  f32x4 acc[4][4];
  #pragma unroll
  for (int i = 0; i < 4; i++)
    #pragma unroll
    for (int j = 0; j < 4; j++)
      acc[i][j] = (f32x4){0.f, 0.f, 0.f, 0.f};

  for (int k0 = 0; k0 < 512; k0 += 32) {
    __syncthreads();
    #pragma unroll
    for (int j = 0; j < 2; j++) {
      int f = j*256 + tid;
      int r = f >> 2, p = f & 3;
      *(short8*)&As[f*8] = *(const short8*)(X  + (m0 + r)*512 + k0 + p*8);
      *(short8*)&Bs[f*8] = *(const short8*)(Wt + (n0 + r)*512 + k0 + p*8);
    }
    __syncthreads();
    short8 af[4], bf[4];
    #pragma unroll
    for (int i = 0; i < 4; i++) af[i] = *(const short8*)&As[(wm + i*16 + l15)*32 + quad*8];
    #pragma unroll
    for (int j = 0; j < 4; j++) bf[j] = *(const short8*)&Bs[(wn + j*16 + l15)*32 + quad*8];
    #pragma unroll
    for (int i = 0; i < 4; i++)
      #pragma unroll
      for (int j = 0; j < 4; j++)
        acc[i][j] = __builtin_amdgcn_mfma_f32_16x16x32_bf16(af[i], bf[j], acc[i][j], 0, 0, 0);
  }

  #pragma unroll
  for (int i = 0; i < 4; i++) {
    #pragma unroll
    for (int j = 0; j < 4; j++) {
      int ncol = n0 + wn + j*16 + l15;
      float bv = bias[ncol];
      #pragma unroll
      for (int r = 0; r < 4; r++) {
        int m = m0 + wm + i*16 + quad*4 + r;   // C/D: row=(lane>>4)*4+reg, col=lane&15
        float val = (acc[i][j][r] + bv) * scale;
        if (mode == 0) {
          ((float*)outp)[m*512 + ncol] = val;
        } else {
          int bb = m >> 10, l = m & 1023, hh = ncol >> 6, d = ncol & 63;
          u16 o = f2bf(val);
          if (mode == 1) ((u16*)outp)[((bb*8 + hh)*1024 + l)*64 + d] = o;
          else           ((u16*)outp)[((bb*8 + hh)*64 + d)*1024 + l] = o;
        }
      }
    }
  }
}

// ---------------- fused attention ----------------
// grid (16, 64): x = q-block (64 rows), y = b*8+h.  256 thr = 4 waves,
// wave w owns q rows [q0+16w, q0+16w+16) over all 1024 keys.
__global__ __launch_bounds__(256, 4) void k_attn(
    const u16* __restrict__ qws, const u16* __restrict__ kws, const u16* __restrict__ vtws,
    const u16* __restrict__ relk80, const u16* __restrict__ relvT,
    const float* __restrict__ tree_emb, const int* __restrict__ rel_matrix,
    const float* __restrict__ rel_mask, const unsigned char* __restrict__ maskp,
    u16* __restrict__ ctx) {
  __shared__ u16 qdotL[64*68];     // [qloc][bucket] bf16, q . rel_emb_k[bucket]
  __shared__ u16 PB[4][16*96];     // per-wave banded P (bucket 0..64, zero-pad to 96)
  __shared__ u16 Kl[32*64];        // [key][dk]
  __shared__ u16 Vl[64*32];        // [dv][key]
  __shared__ u16 Pl[4][16*32];     // per-wave P tile, C-layout -> A-layout bridge
  __shared__ float treec[64];

  int tid = threadIdx.x, lane = tid & 63, wv = tid >> 6;
  int quad = lane >> 4, l15 = lane & 15;
  int qb = blockIdx.x, bh = blockIdx.y;
  int b = bh >> 3, h = bh & 7;
  int q0 = qb * 64;

  if (tid < 64) treec[tid] = tree_emb[tid*8 + h];
  for (int i = tid; i < 4*16*96/2; i += 256) ((u32*)PB)[i] = 0u;

  const u16* qbase = qws  + (size_t)bh * (1024*64);
  const u16* kbase = kws  + (size_t)bh * (1024*64);
  const u16* vbase = vtws + (size_t)bh * (64*1024);
  const int* rmb = rel_matrix + (size_t)b * (1024*1024);
  const float* rkb = rel_mask + (size_t)b * (1024*1024);
  const unsigned char* mkb = maskp + (size_t)b * (1024*1024);

  // Q fragments (A-layout: row=lane&15, k=quad*8+j), q pre-scaled by 1/8
  int qrow = q0 + wv*16 + l15;
  short8 aQ[2];
  aQ[0] = *(const short8*)(qbase + qrow*64 + quad*8);
  aQ[1] = *(const short8*)(qbase + qrow*64 + 32 + quad*8);

  // qdot[qloc][bucket] = q . rel_emb_k[bucket]  (5 bucket tiles of 16)
  #pragma unroll
  for (int t = 0; t < 5; t++) {
    f32x4 C = (f32x4){0.f,0.f,0.f,0.f};
    #pragma unroll
    for (int kf = 0; kf < 2; kf++) {
      short8 bR = *(const short8*)(relk80 + (t*16 + l15)*64 + kf*32 + quad*8);
      C = __builtin_amdgcn_mfma_f32_16x16x32_bf16(aQ[kf], bR, C, 0, 0, 0);
    }
    int col = t*16 + l15;
    if (col < 65) {
      #pragma unroll
      for (int r = 0; r < 4; r++)
        qdotL[(wv*16 + quad*4 + r)*68 + col] = f2bf(C[r]);
    }
  }
  __syncthreads();

  f32x4 O[4];
  #pragma unroll
  for (int t = 0; t < 4; t++) O[t] = (f32x4){0.f,0.f,0.f,0.f};
  float rs[4]  = {0.f,0.f,0.f,0.f};   // row sums (softmax denom)
  float ts0[4] = {0.f,0.f,0.f,0.f};   // bucket-0 tail (k-q <= -32)
  float ts1[4] = {0.f,0.f,0.f,0.f};   // bucket-64 tail (k-q >= 32)

  for (int k0 = 0; k0 < 1024; k0 += 32) {
    __syncthreads();
    {
      int key = tid >> 3, pa = tid & 7;
      *(short8*)&Kl[key*64 + pa*8] = *(const short8*)(kbase + (k0 + key)*64 + pa*8);
      int dv = tid >> 2, pb = tid & 3;
      *(short8*)&Vl[dv*32 + pb*8] = *(const short8*)(vbase + dv*1024 + k0 + pb*8);
    }
    __syncthreads();

    #pragma unroll
    for (int ct = 0; ct < 2; ct++) {
      f32x4 S = (f32x4){0.f,0.f,0.f,0.f};
      #pragma unroll
      for (int kf = 0; kf < 2; kf++) {
        short8 bK = *(const short8*)&Kl[(ct*16 + l15)*64 + kf*32 + quad*8];
        S = __builtin_amdgcn_mfma_f32_16x16x32_bf16(aQ[kf], bK, S, 0, 0, 0);
      }
      int kcol = k0 + ct*16 + l15;
      #pragma unroll
      for (int r = 0; r < 4; r++) {
        int rloc = quad*4 + r;
        int qloc = wv*16 + rloc;
        int qg = q0 + qloc;
        int d = kcol - qg;
        int bucket = (d < -32) ? 0 : ((d > 32) ? 64 : d + 32);
        float s = S[r] + bf2f(qdotL[qloc*68 + bucket]);
        int idx = (qg << 10) + kcol;
        s += treec[rmb[idx] & 63] * rkb[idx];
        float p = mkb[idx] ? 0.0f : __expf(s);   // scores bounded ~|1.4|: no max needed
        rs[r] += p;
        if (d <= -32)      ts0[r] += p;
        else if (d >= 32)  ts1[r] += p;
        else               PB[wv][rloc*96 + bucket] = f2bf(p);  // band: unique (q,k) slot
        Pl[wv][rloc*32 + ct*16 + l15] = f2bf(p);
      }
    }

    // PV: P (A-layout via LDS bridge) @ V[32,64]
    short8 aP = *(const short8*)&Pl[wv][l15*32 + quad*8];
    #pragma unroll
    for (int t = 0; t < 4; t++) {
      short8 bV = *(const short8*)&Vl[(t*16 + l15)*32 + quad*8];
      O[t] = __builtin_amdgcn_mfma_f32_16x16x32_bf16(aP, bV, O[t], 0, 0, 0);
    }
  }

  // row reductions across the 16 lanes of each quad-group
  #pragma unroll
  for (int mres = 1; mres < 16; mres <<= 1) {
    #pragma unroll
    for (int r = 0; r < 4; r++) {
      rs[r]  += __shfl_xor(rs[r],  mres, 64);
      ts0[r] += __shfl_xor(ts0[r], mres, 64);
      ts1[r] += __shfl_xor(ts1[r], mres, 64);
    }
  }
  if (l15 == 0) {
    #pragma unroll
    for (int r = 0; r < 4; r++) {
      PB[wv][(quad*4 + r)*96 + 0]  = f2bf(ts0[r]);
      PB[wv][(quad*4 + r)*96 + 64] = f2bf(ts1[r]);
    }
  }
  __syncthreads();

  // rel_v contribution: PB[16,96] @ relvT^T (buckets 65..95 are zeros)
  short8 aB[3];
  #pragma unroll
  for (int s = 0; s < 3; s++) aB[s] = *(const short8*)&PB[wv][l15*96 + s*32 + quad*8];
  #pragma unroll
  for (int t = 0; t < 4; t++) {
    #pragma unroll
    for (int s = 0; s < 3; s++) {
      short8 bRV = *(const short8*)(relvT + (t*16 + l15)*96 + s*32 + quad*8);
      O[t] = __builtin_amdgcn_mfma_f32_16x16x32_bf16(aB[s], bRV, O[t], 0, 0, 0);
    }
  }

  float inv[4];
  #pragma unroll
  for (int r = 0; r < 4; r++) inv[r] = 1.0f / rs[r];
  #pragma unroll
  for (int t = 0; t < 4; t++) {
    #pragma unroll
    for (int r = 0; r < 4; r++) {
      int qg = q0 + wv*16 + quad*4 + r;
      ctx[(b*1024 + qg)*512 + h*64 + t*16 + l15] = f2bf(O[t][r] * inv[r]);
    }
  }
}

extern "C" void kernel_launch(void* const* d_in, const int* in_sizes, int n_in,
                              void* d_out, int out_size, void* d_ws, size_t ws_size,
                              hipStream_t stream) {
  const float* key   = (const float*)d_in[0];
  const float* value = (const float*)d_in[1];
  const float* query = (const float*)d_in[2];
  const unsigned char* maskp = (const unsigned char*)d_in[3];
  const int*   relm  = (const int*)d_in[4];
  const float* relw  = (const float*)d_in[5];
  const float* Wk = (const float*)d_in[6];
  const float* bk = (const float*)d_in[7];
  const float* Wq = (const float*)d_in[8];
  const float* bq = (const float*)d_in[9];
  const float* Wv = (const float*)d_in[10];
  const float* bv = (const float*)d_in[11];
  const float* Wo = (const float*)d_in[12];
  const float* bo = (const float*)d_in[13];
  const float* rek = (const float*)d_in[14];
  const float* rev = (const float*)d_in[15];
  const float* te  = (const float*)d_in[16];
  (void)in_sizes; (void)n_in; (void)out_size;

  char* w = (char*)d_ws;
  size_t off = 0;
  auto alloc = [&](size_t bytes) -> void* {
    void* p = w + off; off += (bytes + 255) & ~(size_t)255; return p;
  };
  u16* xk  = (u16*)alloc((size_t)8192*512*2);
  u16* xv  = (u16*)alloc((size_t)8192*512*2);
  u16* xq  = (u16*)alloc((size_t)8192*512*2);
  u16* WkT = (u16*)alloc((size_t)512*512*2);
  u16* WqT = (u16*)alloc((size_t)512*512*2);
  u16* WvT = (u16*)alloc((size_t)512*512*2);
  u16* WoT = (u16*)alloc((size_t)512*512*2);
  u16* qws = (u16*)alloc((size_t)8192*512*2);   // [B,H,L,64], pre-scaled 1/8
  u16* kws = (u16*)alloc((size_t)8192*512*2);   // [B,H,L,64]
  u16* vt  = (u16*)alloc((size_t)8192*512*2);   // [B,H,64,L]
  u16* ctxb= (u16*)alloc((size_t)8192*512*2);   // [B,L,512]
  u16* relk80 = (u16*)alloc((size_t)80*64*2);
  u16* relvT  = (u16*)alloc((size_t)64*96*2);
  if (off > ws_size) return;   // consistent every call; fails cleanly if ws too small

  int n4 = 8192*512/4;
  k_cvt<<<n4/256, 256, 0, stream>>>(key,   xk, n4);
  k_cvt<<<n4/256, 256, 0, stream>>>(value, xv, n4);
  k_cvt<<<n4/256, 256, 0, stream>>>(query, xq, n4);
  dim3 gt(16,16);
  k_cvt_wt<<<gt, 256, 0, stream>>>(Wk, WkT);
  k_cvt_wt<<<gt, 256, 0, stream>>>(Wq, WqT);
  k_cvt_wt<<<gt, 256, 0, stream>>>(Wv, WvT);
  k_cvt_wt<<<gt, 256, 0, stream>>>(Wo, WoT);
  k_prep_rel<<<44, 256, 0, stream>>>(rek, rev, relk80, relvT);

  dim3 gg(4, 64);
  k_gemm<<<gg, 256, 0, stream>>>(xq, WqT, bq, (void*)qws, 1, 0.125f);
  k_gemm<<<gg, 256, 0, stream>>>(xk, WkT, bk, (void*)kws, 1, 1.0f);
  k_gemm<<<gg, 256, 0, stream>>>(xv, WvT, bv, (void*)vt,  2, 1.0f);

  dim3 ga(16, 64);
  k_attn<<<ga, 256, 0, stream>>>(qws, kws, vt, relk80, relvT, te, relm, relw, maskp, ctxb);

  k_gemm<<<gg, 256, 0, stream>>>(ctxb, WoT, bo, d_out, 0, 1.0f);
}

// Round 2
// 452.588 us; speedup vs baseline: 1.0236x; 1.0236x over previous
//
#include <hip/hip_runtime.h>
#include <stdint.h>

using f32x4  = __attribute__((ext_vector_type(4))) float;
using short8 = __attribute__((ext_vector_type(8))) short;
typedef unsigned short u16;
typedef unsigned int   u32;

// B=8, H=8, L=1024, DM=512, DK=DV=64.  M = B*L = 8192.

static __device__ __forceinline__ u16 f2bf(float f) {
  union { float f; u32 u; } v; v.f = f;
  u32 r = v.u + 0x7fffu + ((v.u >> 16) & 1u);   // RNE
  return (u16)(r >> 16);
}
static __device__ __forceinline__ float bf2f(u16 u) {
  union { u32 u; float f; } v; v.u = ((u32)u) << 16;
  return v.f;
}

// ---------------- W [512 k][512 n] fp32 -> Wt [n][k] bf16 ----------------
__global__ __launch_bounds__(256) void k_cvt_wt(const float* __restrict__ W,
                                                u16* __restrict__ Wt) {
  __shared__ float t[32][33];
  int tx = threadIdx.x & 31, ty = threadIdx.x >> 5;   // 32 x 8
  int x0 = blockIdx.x * 32, y0 = blockIdx.y * 32;     // x = n, y = k
  #pragma unroll
  for (int i = 0; i < 4; i++)
    t[ty + i*8][tx] = W[(y0 + ty + i*8) * 512 + (x0 + tx)];
  __syncthreads();
  #pragma unroll
  for (int i = 0; i < 4; i++)
    Wt[(x0 + ty + i*8) * 512 + (y0 + tx)] = f2bf(t[tx][ty + i*8]);
}

// ------------- rel embeddings: relk80 [80][64] (zero-pad rows>=65),
//               relvT [64 dv][96 bucket] (zero-pad buckets>=65) -------------
__global__ __launch_bounds__(256) void k_prep_rel(const float* __restrict__ rk,
                                                  const float* __restrict__ rv,
                                                  u16* __restrict__ relk80,
                                                  u16* __restrict__ relvT) {
  int i = blockIdx.x * 256 + threadIdx.x;
  if (i < 80*64) {
    int row = i >> 6;
    relk80[i] = (row < 65) ? f2bf(rk[i]) : (u16)0;
  }
  int j = i - 80*64;
  if (j >= 0 && j < 64*96) {
    int dv = j / 96, bk = j % 96;
    relvT[j] = (bk < 65) ? f2bf(rv[bk*64 + dv]) : (u16)0;
  }
}

// ---------------- bf16 MFMA GEMM: C[8192,512] = X_f32[8192,512] @ Wt^T + bias
// X is fp32, converted to bf16 during LDS staging (no separate cvt pass).
// Wt is [n][k] bf16.  Tiles: M=128, N=64 -> grid (8, 64) = 512 blocks.
// mode 0: fp32 out, plain [m][n] (d_out).
// mode 1: bf16 out at [b,h,l,d] (q/k; q uses scale=0.125)
// mode 2: bf16 out at [b,h,d,l] (v transposed)
__global__ __launch_bounds__(256) void k_gemm(const float* __restrict__ X,
                                              const u16* __restrict__ Wt,
                                              const float* __restrict__ bias,
                                              void* __restrict__ outp,
                                              int mode, float scale) {
  __shared__ u16 As[128*32];   // [m][k]
  __shared__ u16 Bs[64*32];    // [n][k]
  int tid = threadIdx.x;
  int lane = tid & 63, wv = tid >> 6;
  int quad = lane >> 4, l15 = lane & 15;
  int n0 = blockIdx.x * 64, m0 = blockIdx.y * 128;
  int wm = wv * 32;
  f32x4 acc[2][4];
  #pragma unroll
  for (int i = 0; i < 2; i++)
    #pragma unroll
    for (int j = 0; j < 4; j++)
      acc[i][j] = (f32x4){0.f, 0.f, 0.f, 0.f};

  // staging maps
  int arow = tid >> 3, apos = tid & 7;            // + 32*j rows via f = tid + 256j
  int brow = tid >> 2, bpos = tid & 3;

  // prologue: tile 0 into regs
  float4 areg[4]; short8 breg;
  #pragma unroll
  for (int j = 0; j < 4; j++) {
    int f = tid + 256*j; int r = f >> 3, p = f & 7;
    areg[j] = ((const float4*)(X + (m0 + r)*512 + p*4))[0];
  }
  breg = *(const short8*)(Wt + (n0 + brow)*512 + bpos*8);

  for (int k0 = 0; k0 < 512; k0 += 32) {
    __syncthreads();
    #pragma unroll
    for (int j = 0; j < 4; j++) {
      int f = tid + 256*j; int r = f >> 3, p = f & 7;
      ushort4 o;
      o.x = f2bf(areg[j].x); o.y = f2bf(areg[j].y);
      o.z = f2bf(areg[j].z); o.w = f2bf(areg[j].w);
      *(ushort4*)&As[r*32 + p*4] = o;
    }
    *(short8*)&Bs[brow*32 + bpos*8] = breg;
    __syncthreads();
    // prefetch next tile (wrap to 0 on last iter; values unused)
    int kn = (k0 + 32 < 512) ? (k0 + 32) : 0;
    #pragma unroll
    for (int j = 0; j < 4; j++) {
      int f = tid + 256*j; int r = f >> 3, p = f & 7;
      areg[j] = ((const float4*)(X + (m0 + r)*512 + kn + p*4))[0];
    }
    breg = *(const short8*)(Wt + (n0 + brow)*512 + kn + bpos*8);

    short8 af[2], bfr[4];
    #pragma unroll
    for (int i = 0; i < 2; i++) af[i] = *(const short8*)&As[(wm + i*16 + l15)*32 + quad*8];
    #pragma unroll
    for (int j = 0; j < 4; j++) bfr[j] = *(const short8*)&Bs[(j*16 + l15)*32 + quad*8];
    #pragma unroll
    for (int i = 0; i < 2; i++)
      #pragma unroll
      for (int j = 0; j < 4; j++)
        acc[i][j] = __builtin_amdgcn_mfma_f32_16x16x32_bf16(af[i], bfr[j], acc[i][j], 0, 0, 0);
  }

  #pragma unroll
  for (int i = 0; i < 2; i++) {
    #pragma unroll
    for (int j = 0; j < 4; j++) {
      int ncol = n0 + j*16 + l15;
      float bv = bias[ncol];
      #pragma unroll
      for (int r = 0; r < 4; r++) {
        int m = m0 + wm + i*16 + quad*4 + r;   // C/D: row=(lane>>4)*4+reg, col=lane&15
        float val = (acc[i][j][r] + bv) * scale;
        if (mode == 0) {
          ((float*)outp)[m*512 + ncol] = val;
        } else {
          int bb = m >> 10, l = m & 1023, hh = ncol >> 6, d = ncol & 63;
          u16 o = f2bf(val);
          if (mode == 1) ((u16*)outp)[((bb*8 + hh)*1024 + l)*64 + d] = o;
          else           ((u16*)outp)[((bb*8 + hh)*64 + d)*1024 + l] = o;
        }
      }
    }
  }
}

// ---------------- fused attention ----------------
// grid (16, 64): x = q-block (64 rows), y = b*8+h.  256 thr = 4 waves,
// wave w owns q rows [q0+16w, q0+16w+16) over all 1024 keys.
// Software-pipelined: K/V tile + per-lane rel/mask gathers prefetched into
// registers one k-tile ahead (the R1 profile was latency-stall bound:
// VALUBusy 23%, MfmaUtil 3.4%, HBM 6.7%).
__global__ __launch_bounds__(256, 4) void k_attn(
    const u16* __restrict__ qws, const u16* __restrict__ kws, const u16* __restrict__ vtws,
    const u16* __restrict__ relk80, const u16* __restrict__ relvT,
    const float* __restrict__ tree_emb, const int* __restrict__ rel_matrix,
    const float* __restrict__ rel_mask, const unsigned char* __restrict__ maskp,
    float* __restrict__ ctx) {
  __shared__ u16 qdotL[64*68];     // [qloc][bucket] bf16, q . rel_emb_k[bucket]
  __shared__ u16 PB[4][16*96];     // per-wave banded P (bucket 0..64, zero-pad to 96)
  __shared__ u16 Kl[32*64];        // [key][dk]
  __shared__ u16 Vl[64*32];        // [dv][key]
  __shared__ u16 Pl[4][16*32];     // per-wave P tile, C-layout -> A-layout bridge
  __shared__ float treec[64];

  int tid = threadIdx.x, lane = tid & 63, wv = tid >> 6;
  int quad = lane >> 4, l15 = lane & 15;
  int qb = blockIdx.x, bh = blockIdx.y;
  int b = bh >> 3, h = bh & 7;
  int q0 = qb * 64;

  if (tid < 64) treec[tid] = tree_emb[tid*8 + h];
  for (int i = tid; i < 4*16*96/2; i += 256) ((u32*)PB)[i] = 0u;

  const u16* qbase = qws  + (size_t)bh * (1024*64);
  const u16* kbase = kws  + (size_t)bh * (1024*64);
  const u16* vbase = vtws + (size_t)bh * (64*1024);
  const int* rmb = rel_matrix + (size_t)b * (1024*1024);
  const float* rkb = rel_mask + (size_t)b * (1024*1024);
  const unsigned char* mkb = maskp + (size_t)b * (1024*1024);

  // Q fragments (A-layout: row=lane&15, k=quad*8+j), q pre-scaled by 1/8
  int qrl = wv*16 + quad*4;          // first of this lane's 4 q-rows (local)
  int qrow = q0 + wv*16 + l15;
  short8 aQ[2];
  aQ[0] = *(const short8*)(qbase + qrow*64 + quad*8);
  aQ[1] = *(const short8*)(qbase + qrow*64 + 32 + quad*8);

  // qdot[qloc][bucket] = q . rel_emb_k[bucket]  (5 bucket tiles of 16)
  #pragma unroll
  for (int t = 0; t < 5; t++) {
    f32x4 C = (f32x4){0.f,0.f,0.f,0.f};
    #pragma unroll
    for (int kf = 0; kf < 2; kf++) {
      short8 bR = *(const short8*)(relk80 + (t*16 + l15)*64 + kf*32 + quad*8);
      C = __builtin_amdgcn_mfma_f32_16x16x32_bf16(aQ[kf], bR, C, 0, 0, 0);
    }
    int col = t*16 + l15;
    if (col < 65) {
      #pragma unroll
      for (int r = 0; r < 4; r++)
        qdotL[(wv*16 + quad*4 + r)*68 + col] = f2bf(C[r]);
    }
  }
  __syncthreads();

  // K/V staging prefetch (regs hold next tile)
  int keyr = tid >> 3, pa = tid & 7;
  int dvr  = tid >> 2, pb2 = tid & 3;
  const u16* kptr = kbase + keyr*64 + pa*8;     // + k0*64
  const u16* vptr = vbase + dvr*1024 + pb2*8;   // + k0
  short8 kreg = *(const short8*)(kptr);
  short8 vreg = *(const short8*)(vptr);

  // rel/mask gather prefetch (regs hold current tile's 8 elements)
  int rbase = ((q0 + qrl) << 10) + l15;         // + (r<<10) + k0 + ct*16
  int   rm_c[8]; float rw_c[8]; u32 mk_c[8];
  #pragma unroll
  for (int e = 0; e < 8; e++) {
    int ct = e >> 2, r = e & 3;
    int idx = rbase + (r << 10) + ct*16;
    rm_c[e] = rmb[idx]; rw_c[e] = rkb[idx]; mk_c[e] = mkb[idx];
  }

  f32x4 O[4];
  #pragma unroll
  for (int t = 0; t < 4; t++) O[t] = (f32x4){0.f,0.f,0.f,0.f};
  float rs[4]  = {0.f,0.f,0.f,0.f};   // row sums (softmax denom)
  float ts0[4] = {0.f,0.f,0.f,0.f};   // bucket-0 tail (k-q <= -32)
  float ts1[4] = {0.f,0.f,0.f,0.f};   // bucket-64 tail (k-q >= 32)

  for (int it = 0; it < 32; ++it) {
    int k0 = it << 5;
    int kn = (it + 1 < 32) ? (k0 + 32) : 0;   // wrap: valid addr, values unused
    __syncthreads();
    *(short8*)&Kl[keyr*64 + pa*8] = kreg;
    *(short8*)&Vl[dvr*32  + pb2*8] = vreg;
    __syncthreads();
    kreg = *(const short8*)(kptr + kn*64);
    vreg = *(const short8*)(vptr + kn);

    // phase 1: fold qdot + tree-bias + mask into bias8 (consumes prefetched regs)
    float bias8[8];
    #pragma unroll
    for (int e = 0; e < 8; e++) {
      int ct = e >> 2, r = e & 3;
      int kcol = k0 + ct*16 + l15;
      int d = kcol - (q0 + qrl + r);
      int bucket = min(max(d + 32, 0), 64);
      float qd = bf2f(qdotL[(qrl + wv*16 - wv*16 + qrl*0 + (wv*16 + quad*4 + r))*0 + (wv*16 + quad*4 + r)*68 + bucket]);
      float tb = treec[rm_c[e] & 63] * rw_c[e];
      bias8[e] = mk_c[e] ? -1e30f : (qd + tb);   // exp(s-1e30) == 0 handles mask
    }
    // phase 2: issue next tile's gathers (land during MFMAs + p-chain + barriers)
    #pragma unroll
    for (int e = 0; e < 8; e++) {
      int ct = e >> 2, r = e & 3;
      int idx = rbase + (r << 10) + kn + ct*16;
      rm_c[e] = rmb[idx]; rw_c[e] = rkb[idx]; mk_c[e] = mkb[idx];
    }
    // phase 3: QK^T MFMA + p
    #pragma unroll
    for (int ct = 0; ct < 2; ct++) {
      f32x4 S = (f32x4){0.f,0.f,0.f,0.f};
      #pragma unroll
      for (int kf = 0; kf < 2; kf++) {
        short8 bK = *(const short8*)&Kl[(ct*16 + l15)*64 + kf*32 + quad*8];
        S = __builtin_amdgcn_mfma_f32_16x16x32_bf16(aQ[kf], bK, S, 0, 0, 0);
      }
      int kcol = k0 + ct*16 + l15;
      #pragma unroll
      for (int r = 0; r < 4; r++) {
        int rloc = quad*4 + r;
        float p = __expf(S[r] + bias8[ct*4 + r]);
        rs[r] += p;
        int d = kcol - (q0 + wv*16 + rloc);
        if (d <= -32)      ts0[r] += p;
        else if (d >= 32)  ts1[r] += p;
        else               PB[wv][rloc*96 + d + 32] = f2bf(p);
        Pl[wv][rloc*32 + ct*16 + l15] = f2bf(p);
      }
    }
    // phase 4: PV (P via per-wave LDS bridge: C-layout -> A-layout)
    short8 aP = *(const short8*)&Pl[wv][l15*32 + quad*8];
    #pragma unroll
    for (int t = 0; t < 4; t++) {
      short8 bV = *(const short8*)&Vl[(t*16 + l15)*32 + quad*8];
      O[t] = __builtin_amdgcn_mfma_f32_16x16x32_bf16(aP, bV, O[t], 0, 0, 0);
    }
  }

  // row reductions across the 16 lanes of each quad-group
  #pragma unroll
  for (int mres = 1; mres < 16; mres <<= 1) {
    #pragma unroll
    for (int r = 0; r < 4; r++) {
      rs[r]  += __shfl_xor(rs[r],  mres, 64);
      ts0[r] += __shfl_xor(ts0[r], mres, 64);
      ts1[r] += __shfl_xor(ts1[r], mres, 64);
    }
  }
  if (l15 == 0) {
    #pragma unroll
    for (int r = 0; r < 4; r++) {
      PB[wv][(quad*4 + r)*96 + 0]  = f2bf(ts0[r]);
      PB[wv][(quad*4 + r)*96 + 64] = f2bf(ts1[r]);
    }
  }
  __syncthreads();

  // rel_v contribution: PB[16,96] @ relvT^T (buckets 65..95 are zeros)
  short8 aB[3];
  #pragma unroll
  for (int s = 0; s < 3; s++) aB[s] = *(const short8*)&PB[wv][l15*96 + s*32 + quad*8];
  #pragma unroll
  for (int t = 0; t < 4; t++) {
    #pragma unroll
    for (int s = 0; s < 3; s++) {
      short8 bRV = *(const short8*)(relvT + (t*16 + l15)*96 + s*32 + quad*8);
      O[t] = __builtin_amdgcn_mfma_f32_16x16x32_bf16(aB[s], bRV, O[t], 0, 0, 0);
    }
  }

  float inv[4];
  #pragma unroll
  for (int r = 0; r < 4; r++) inv[r] = 1.0f / rs[r];
  #pragma unroll
  for (int t = 0; t < 4; t++) {
    #pragma unroll
    for (int r = 0; r < 4; r++) {
      int qg = q0 + wv*16 + quad*4 + r;
      ctx[(b*1024 + qg)*512 + h*64 + t*16 + l15] = O[t][r] * inv[r];
    }
  }
}

extern "C" void kernel_launch(void* const* d_in, const int* in_sizes, int n_in,
                              void* d_out, int out_size, void* d_ws, size_t ws_size,
                              hipStream_t stream) {
  const float* key   = (const float*)d_in[0];
  const float* value = (const float*)d_in[1];
  const float* query = (const float*)d_in[2];
  const unsigned char* maskp = (const unsigned char*)d_in[3];
  const int*   relm  = (const int*)d_in[4];
  const float* relw  = (const float*)d_in[5];
  const float* Wk = (const float*)d_in[6];
  const float* bk = (const float*)d_in[7];
  const float* Wq = (const float*)d_in[8];
  const float* bq = (const float*)d_in[9];
  const float* Wv = (const float*)d_in[10];
  const float* bv = (const float*)d_in[11];
  const float* Wo = (const float*)d_in[12];
  const float* bo = (const float*)d_in[13];
  const float* rek = (const float*)d_in[14];
  const float* rev = (const float*)d_in[15];
  const float* te  = (const float*)d_in[16];
  (void)in_sizes; (void)n_in; (void)out_size;

  char* w = (char*)d_ws;
  size_t off = 0;
  auto alloc = [&](size_t bytes) -> void* {
    void* p = w + off; off += (bytes + 255) & ~(size_t)255; return p;
  };
  u16* WkT = (u16*)alloc((size_t)512*512*2);
  u16* WqT = (u16*)alloc((size_t)512*512*2);
  u16* WvT = (u16*)alloc((size_t)512*512*2);
  u16* WoT = (u16*)alloc((size_t)512*512*2);
  u16* qws = (u16*)alloc((size_t)8192*64*2*8);   // [B,H,L,64], pre-scaled 1/8
  u16* kws = (u16*)alloc((size_t)8192*64*2*8);   // [B,H,L,64]
  u16* vt  = (u16*)alloc((size_t)8192*64*2*8);   // [B,H,64,L]
  float* ctxb = (float*)alloc((size_t)8192*512*4); // [B,L,512] fp32
  u16* relk80 = (u16*)alloc((size_t)80*64*2);
  u16* relvT  = (u16*)alloc((size_t)64*96*2);
  if (off > ws_size) return;

  dim3 gt(16,16);
  k_cvt_wt<<<gt, 256, 0, stream>>>(Wk, WkT);
  k_cvt_wt<<<gt, 256, 0, stream>>>(Wq, WqT);
  k_cvt_wt<<<gt, 256, 0, stream>>>(Wv, WvT);
  k_cvt_wt<<<gt, 256, 0, stream>>>(Wo, WoT);
  k_prep_rel<<<44, 256, 0, stream>>>(rek, rev, relk80, relvT);

  dim3 gg(8, 64);
  k_gemm<<<gg, 256, 0, stream>>>(query, WqT, bq, (void*)qws, 1, 0.125f);
  k_gemm<<<gg, 256, 0, stream>>>(key,   WkT, bk, (void*)kws, 1, 1.0f);
  k_gemm<<<gg, 256, 0, stream>>>(value, WvT, bv, (void*)vt,  2, 1.0f);

  dim3 ga(16, 64);
  k_attn<<<ga, 256, 0, stream>>>(qws, kws, vt, relk80, relvT, te, relm, relw, maskp, ctxb);

  k_gemm<<<gg, 256, 0, stream>>>(ctxb, WoT, bo, d_out, 0, 1.0f);
}

// Round 3
// 406.123 us; speedup vs baseline: 1.1407x; 1.1144x over previous
//
#include <hip/hip_runtime.h>
#include <stdint.h>

using f32x4  = __attribute__((ext_vector_type(4))) float;
using short8 = __attribute__((ext_vector_type(8))) short;
typedef unsigned short u16;
typedef unsigned int   u32;

// B=8, H=8, L=1024, DM=512, DK=DV=64.  M = B*L = 8192.

static __device__ __forceinline__ u16 f2bf(float f) {
  union { float f; u32 u; } v; v.f = f;
  u32 r = v.u + 0x7fffu + ((v.u >> 16) & 1u);   // RNE
  return (u16)(r >> 16);
}
static __device__ __forceinline__ float bf2f(u16 u) {
  union { u32 u; float f; } v; v.u = ((u32)u) << 16;
  return v.f;
}

// ---------------- W [512 k][512 n] fp32 -> Wt [n][k] bf16 ----------------
__global__ __launch_bounds__(256) void k_cvt_wt(const float* __restrict__ W,
                                                u16* __restrict__ Wt) {
  __shared__ float t[32][33];
  int tx = threadIdx.x & 31, ty = threadIdx.x >> 5;   // 32 x 8
  int x0 = blockIdx.x * 32, y0 = blockIdx.y * 32;     // x = n, y = k
  #pragma unroll
  for (int i = 0; i < 4; i++)
    t[ty + i*8][tx] = W[(y0 + ty + i*8) * 512 + (x0 + tx)];
  __syncthreads();
  #pragma unroll
  for (int i = 0; i < 4; i++)
    Wt[(x0 + ty + i*8) * 512 + (y0 + tx)] = f2bf(t[tx][ty + i*8]);
}

// ------------- rel embeddings: relk80 [80][64] (zero-pad rows>=65),
//               relvT [64 dv][96 bucket] (zero-pad buckets>=65) -------------
__global__ __launch_bounds__(256) void k_prep_rel(const float* __restrict__ rk,
                                                  const float* __restrict__ rv,
                                                  u16* __restrict__ relk80,
                                                  u16* __restrict__ relvT) {
  int i = blockIdx.x * 256 + threadIdx.x;
  if (i < 80*64) {
    int row = i >> 6;
    relk80[i] = (row < 65) ? f2bf(rk[i]) : (u16)0;
  }
  int j = i - 80*64;
  if (j >= 0 && j < 64*96) {
    int dv = j / 96, bk = j % 96;
    relvT[j] = (bk < 65) ? f2bf(rv[bk*64 + dv]) : (u16)0;
  }
}

// ---------------- bf16 MFMA GEMM: C[8192,512] = X_f32[8192,512] @ Wt^T + bias
__global__ __launch_bounds__(256) void k_gemm(const float* __restrict__ X,
                                              const u16* __restrict__ Wt,
                                              const float* __restrict__ bias,
                                              void* __restrict__ outp,
                                              int mode, float scale) {
  __shared__ u16 As[128*32];   // [m][k]
  __shared__ u16 Bs[64*32];    // [n][k]
  int tid = threadIdx.x;
  int lane = tid & 63, wv = tid >> 6;
  int quad = lane >> 4, l15 = lane & 15;
  int n0 = blockIdx.x * 64, m0 = blockIdx.y * 128;
  int wm = wv * 32;
  f32x4 acc[2][4];
  #pragma unroll
  for (int i = 0; i < 2; i++)
    #pragma unroll
    for (int j = 0; j < 4; j++)
      acc[i][j] = (f32x4){0.f, 0.f, 0.f, 0.f};

  int brow = tid >> 2, bpos = tid & 3;

  float4 areg[4]; short8 breg;
  #pragma unroll
  for (int j = 0; j < 4; j++) {
    int f = tid + 256*j; int r = f >> 3, p = f & 7;
    areg[j] = ((const float4*)(X + (m0 + r)*512 + p*4))[0];
  }
  breg = *(const short8*)(Wt + (n0 + brow)*512 + bpos*8);

  for (int k0 = 0; k0 < 512; k0 += 32) {
    __syncthreads();
    #pragma unroll
    for (int j = 0; j < 4; j++) {
      int f = tid + 256*j; int r = f >> 3, p = f & 7;
      ushort4 o;
      o.x = f2bf(areg[j].x); o.y = f2bf(areg[j].y);
      o.z = f2bf(areg[j].z); o.w = f2bf(areg[j].w);
      *(ushort4*)&As[r*32 + p*4] = o;
    }
    *(short8*)&Bs[brow*32 + bpos*8] = breg;
    __syncthreads();
    int kn = (k0 + 32 < 512) ? (k0 + 32) : 0;
    #pragma unroll
    for (int j = 0; j < 4; j++) {
      int f = tid + 256*j; int r = f >> 3, p = f & 7;
      areg[j] = ((const float4*)(X + (m0 + r)*512 + kn + p*4))[0];
    }
    breg = *(const short8*)(Wt + (n0 + brow)*512 + kn + bpos*8);

    short8 af[2], bfr[4];
    #pragma unroll
    for (int i = 0; i < 2; i++) af[i] = *(const short8*)&As[(wm + i*16 + l15)*32 + quad*8];
    #pragma unroll
    for (int j = 0; j < 4; j++) bfr[j] = *(const short8*)&Bs[(j*16 + l15)*32 + quad*8];
    #pragma unroll
    for (int i = 0; i < 2; i++)
      #pragma unroll
      for (int j = 0; j < 4; j++)
        acc[i][j] = __builtin_amdgcn_mfma_f32_16x16x32_bf16(af[i], bfr[j], acc[i][j], 0, 0, 0);
  }

  #pragma unroll
  for (int i = 0; i < 2; i++) {
    #pragma unroll
    for (int j = 0; j < 4; j++) {
      int ncol = n0 + j*16 + l15;
      float bv = bias[ncol];
      #pragma unroll
      for (int r = 0; r < 4; r++) {
        int m = m0 + wm + i*16 + quad*4 + r;
        float val = (acc[i][j][r] + bv) * scale;
        if (mode == 0) {
          ((float*)outp)[m*512 + ncol] = val;
        } else {
          int bb = m >> 10, l = m & 1023, hh = ncol >> 6, d = ncol & 63;
          u16 o = f2bf(val);
          if (mode == 1) ((u16*)outp)[((bb*8 + hh)*1024 + l)*64 + d] = o;
          else           ((u16*)outp)[((bb*8 + hh)*64 + d)*1024 + l] = o;
        }
      }
    }
  }
}

// ---------------- fused attention, cross-head amortized ----------------
// grid 512: b = blockIdx&7 (XCD-clusters K/V per batch), qt = blockIdx>>3.
// Block: q-tile of 16 rows, ALL 8 heads, all 1024 keys.  4 waves; wave w
// owns heads {w, w+4}.  rel_matrix/rel_mask/mask staged ONCE per block into
// LDS packed 4B/elem and consumed by both heads of every wave (R2 showed the
// per-head gather re-reads tripled HBM fetch and pinned dur at 211us).
__global__ __launch_bounds__(256, 2) void k_attn(
    const u16* __restrict__ qws, const u16* __restrict__ kws, const u16* __restrict__ vtws,
    const u16* __restrict__ relk80, const u16* __restrict__ relvT,
    const float* __restrict__ tree_emb, const int* __restrict__ rel_matrix,
    const float* __restrict__ rel_mask, const unsigned char* __restrict__ maskp,
    float* __restrict__ ctx) {
  __shared__ u16 qdotL[8*16*68];    // [h][q][bucket]
  __shared__ u16 PB[8][16*96];      // per-head banded P
  __shared__ u16 Pl[4][2][16*32];   // per-wave, per-head C->A bridge
  __shared__ u32 staged[16*32];     // packed rm|mk<<7|bf16(rw)<<16
  __shared__ float treecT[8*64];    // [h][vocab]

  int tid = threadIdx.x, lane = tid & 63, wv = tid >> 6;
  int quad = lane >> 4, l15 = lane & 15;
  int b = blockIdx.x & 7, qt = blockIdx.x >> 3;
  int q0 = qt * 16;

  for (int i = tid; i < 512; i += 256) treecT[(i & 7)*64 + (i >> 3)] = tree_emb[i];
  for (int i = tid; i < 8*16*96/2; i += 256) ((u32*)PB)[i] = 0u;

  const u16* qb[2] = { qws + (size_t)(b*8 + wv)*(1024*64),
                       qws + (size_t)(b*8 + wv + 4)*(1024*64) };
  const u16* kb[2] = { kws + (size_t)(b*8 + wv)*(1024*64),
                       kws + (size_t)(b*8 + wv + 4)*(1024*64) };
  const u16* vb[2] = { vtws + (size_t)(b*8 + wv)*(64*1024),
                       vtws + (size_t)(b*8 + wv + 4)*(64*1024) };
  const int* rmb = rel_matrix + ((size_t)b << 20);
  const float* rkb = rel_mask + ((size_t)b << 20);
  const unsigned char* mkb = maskp + ((size_t)b << 20);

  // Q fragments (A-layout), q pre-scaled by 1/8
  short8 aQ[2][2];
  #pragma unroll
  for (int h2 = 0; h2 < 2; h2++)
    #pragma unroll
    for (int kf = 0; kf < 2; kf++)
      aQ[h2][kf] = *(const short8*)(qb[h2] + (q0 + l15)*64 + kf*32 + quad*8);

  // qdot[h][q][bucket] = q . rel_emb_k[bucket]
  #pragma unroll
  for (int h2 = 0; h2 < 2; h2++) {
    #pragma unroll
    for (int t = 0; t < 5; t++) {
      f32x4 C = (f32x4){0.f,0.f,0.f,0.f};
      #pragma unroll
      for (int kf = 0; kf < 2; kf++) {
        short8 bR = *(const short8*)(relk80 + (t*16 + l15)*64 + kf*32 + quad*8);
        C = __builtin_amdgcn_mfma_f32_16x16x32_bf16(aQ[h2][kf], bR, C, 0, 0, 0);
      }
      int col = t*16 + l15;
      if (col < 65) {
        #pragma unroll
        for (int r = 0; r < 4; r++)
          qdotL[((wv + h2*4)*16 + quad*4 + r)*68 + col] = f2bf(C[r]);
      }
    }
  }

  // staged-rel prefetch (tile 0)
  int srow = tid >> 4, scol = (tid & 15)*2;
  const int* rm_p = rmb + ((q0 + srow) << 10) + scol;
  const float* rw_p = rkb + ((q0 + srow) << 10) + scol;
  const unsigned char* mk_p = mkb + ((q0 + srow) << 10) + scol;
  int2   rmr = *(const int2*)rm_p;
  float2 rwr = *(const float2*)rw_p;
  u16    mkr = *(const u16*)mk_p;

  // K prefetch (tile 0)
  short8 kreg[2][2][2];
  #pragma unroll
  for (int h2 = 0; h2 < 2; h2++)
    #pragma unroll
    for (int ct = 0; ct < 2; ct++)
      #pragma unroll
      for (int kf = 0; kf < 2; kf++)
        kreg[h2][ct][kf] = *(const short8*)(kb[h2] + (ct*16 + l15)*64 + kf*32 + quad*8);

  f32x4 O[2][4];
  float rs[2][4], ts0[2][4], ts1[2][4];
  #pragma unroll
  for (int h2 = 0; h2 < 2; h2++) {
    #pragma unroll
    for (int t = 0; t < 4; t++) O[h2][t] = (f32x4){0.f,0.f,0.f,0.f};
    #pragma unroll
    for (int r = 0; r < 4; r++) { rs[h2][r] = 0.f; ts0[h2][r] = 0.f; ts1[h2][r] = 0.f; }
  }

  for (int it = 0; it < 32; ++it) {
    int k0 = it << 5;
    int kn = (it + 1 < 32) ? (k0 + 32) : 0;   // wrap: valid addr, values unused
    __syncthreads();
    {
      u32 p0 = (u32)(rmr.x & 63) | ((u32)(mkr & 0xffu) << 7) | ((u32)f2bf(rwr.x) << 16);
      u32 p1 = (u32)(rmr.y & 63) | ((u32)(mkr >> 8) << 7)    | ((u32)f2bf(rwr.y) << 16);
      staged[srow*32 + scol]     = p0;
      staged[srow*32 + scol + 1] = p1;
    }
    __syncthreads();
    // next staged-rel tile
    rmr = *(const int2*)(rm_p + kn);
    rwr = *(const float2*)(rw_p + kn);
    mkr = *(const u16*)(mk_p + kn);
    // V for current tile (consumed late this iter)
    short8 vreg[2][4];
    #pragma unroll
    for (int h2 = 0; h2 < 2; h2++)
      #pragma unroll
      for (int t = 0; t < 4; t++)
        vreg[h2][t] = *(const short8*)(vb[h2] + (t*16 + l15)*1024 + k0 + quad*8);

    // QK^T from prefetched K
    f32x4 S[2][2];
    #pragma unroll
    for (int h2 = 0; h2 < 2; h2++)
      #pragma unroll
      for (int ct = 0; ct < 2; ct++) {
        f32x4 c = (f32x4){0.f,0.f,0.f,0.f};
        #pragma unroll
        for (int kf = 0; kf < 2; kf++)
          c = __builtin_amdgcn_mfma_f32_16x16x32_bf16(aQ[h2][kf], kreg[h2][ct][kf], c, 0, 0, 0);
        S[h2][ct] = c;
      }
    // next K tile
    #pragma unroll
    for (int h2 = 0; h2 < 2; h2++)
      #pragma unroll
      for (int ct = 0; ct < 2; ct++)
        #pragma unroll
        for (int kf = 0; kf < 2; kf++)
          kreg[h2][ct][kf] = *(const short8*)(kb[h2] + (kn + ct*16 + l15)*64 + kf*32 + quad*8);

    // elementwise: staged read amortized over both heads
    #pragma unroll
    for (int ct = 0; ct < 2; ct++) {
      #pragma unroll
      for (int r = 0; r < 4; r++) {
        int kloc = ct*16 + l15, qloc = quad*4 + r;
        u32 sg = staged[qloc*32 + kloc];
        int d = (k0 + kloc) - (q0 + qloc);
        int bucket = min(max(d + 32, 0), 64);
        float rw = bf2f((u16)(sg >> 16));
        float mb = (sg & 128u) ? -1e30f : 0.0f;
        int rm = sg & 63u;
        #pragma unroll
        for (int h2 = 0; h2 < 2; h2++) {
          float qd = bf2f(qdotL[((wv + h2*4)*16 + qloc)*68 + bucket]);
          float tb = treecT[(wv + h2*4)*64 + rm];
          float p = __expf(S[h2][ct][r] + qd + tb*rw + mb);
          rs[h2][r] += p;
          if (d <= -32)      ts0[h2][r] += p;
          else if (d >= 32)  ts1[h2][r] += p;
          else               PB[wv + h2*4][qloc*96 + d + 32] = f2bf(p);
          Pl[wv][h2][qloc*32 + kloc] = f2bf(p);
        }
      }
    }

    // PV (bridge Pl: C-layout -> A-layout, within-wave)
    #pragma unroll
    for (int h2 = 0; h2 < 2; h2++) {
      short8 aP = *(const short8*)&Pl[wv][h2][l15*32 + quad*8];
      #pragma unroll
      for (int t = 0; t < 4; t++)
        O[h2][t] = __builtin_amdgcn_mfma_f32_16x16x32_bf16(aP, vreg[h2][t], O[h2][t], 0, 0, 0);
    }
  }

  // row sums across the 16 lanes of each quad-group
  #pragma unroll
  for (int m = 1; m < 16; m <<= 1) {
    #pragma unroll
    for (int h2 = 0; h2 < 2; h2++)
      #pragma unroll
      for (int r = 0; r < 4; r++) {
        rs[h2][r]  += __shfl_xor(rs[h2][r],  m, 64);
        ts0[h2][r] += __shfl_xor(ts0[h2][r], m, 64);
        ts1[h2][r] += __shfl_xor(ts1[h2][r], m, 64);
      }
  }
  if (l15 == 0) {
    #pragma unroll
    for (int h2 = 0; h2 < 2; h2++)
      #pragma unroll
      for (int r = 0; r < 4; r++) {
        PB[wv + h2*4][(quad*4 + r)*96 + 0]  = f2bf(ts0[h2][r]);
        PB[wv + h2*4][(quad*4 + r)*96 + 64] = f2bf(ts1[h2][r]);
      }
  }
  __syncthreads();

  // rel_v: PB[16,96] @ relvT^T
  #pragma unroll
  for (int h2 = 0; h2 < 2; h2++) {
    short8 aB[3];
    #pragma unroll
    for (int s = 0; s < 3; s++)
      aB[s] = *(const short8*)&PB[wv + h2*4][l15*96 + s*32 + quad*8];
    #pragma unroll
    for (int t = 0; t < 4; t++)
      #pragma unroll
      for (int s = 0; s < 3; s++) {
        short8 bRV = *(const short8*)(relvT + (t*16 + l15)*96 + s*32 + quad*8);
        O[h2][t] = __builtin_amdgcn_mfma_f32_16x16x32_bf16(aB[s], bRV, O[h2][t], 0, 0, 0);
      }
  }

  #pragma unroll
  for (int h2 = 0; h2 < 2; h2++) {
    float inv[4];
    #pragma unroll
    for (int r = 0; r < 4; r++) inv[r] = 1.0f / rs[h2][r];
    #pragma unroll
    for (int t = 0; t < 4; t++)
      #pragma unroll
      for (int r = 0; r < 4; r++) {
        int qg = q0 + quad*4 + r;
        ctx[(b*1024 + qg)*512 + (wv + h2*4)*64 + t*16 + l15] = O[h2][t][r] * inv[r];
      }
  }
}

extern "C" void kernel_launch(void* const* d_in, const int* in_sizes, int n_in,
                              void* d_out, int out_size, void* d_ws, size_t ws_size,
                              hipStream_t stream) {
  const float* key   = (const float*)d_in[0];
  const float* value = (const float*)d_in[1];
  const float* query = (const float*)d_in[2];
  const unsigned char* maskp = (const unsigned char*)d_in[3];
  const int*   relm  = (const int*)d_in[4];
  const float* relw  = (const float*)d_in[5];
  const float* Wk = (const float*)d_in[6];
  const float* bk = (const float*)d_in[7];
  const float* Wq = (const float*)d_in[8];
  const float* bq = (const float*)d_in[9];
  const float* Wv = (const float*)d_in[10];
  const float* bv = (const float*)d_in[11];
  const float* Wo = (const float*)d_in[12];
  const float* bo = (const float*)d_in[13];
  const float* rek = (const float*)d_in[14];
  const float* rev = (const float*)d_in[15];
  const float* te  = (const float*)d_in[16];
  (void)in_sizes; (void)n_in; (void)out_size;

  char* w = (char*)d_ws;
  size_t off = 0;
  auto alloc = [&](size_t bytes) -> void* {
    void* p = w + off; off += (bytes + 255) & ~(size_t)255; return p;
  };
  u16* WkT = (u16*)alloc((size_t)512*512*2);
  u16* WqT = (u16*)alloc((size_t)512*512*2);
  u16* WvT = (u16*)alloc((size_t)512*512*2);
  u16* WoT = (u16*)alloc((size_t)512*512*2);
  u16* qws = (u16*)alloc((size_t)8192*64*2*8);   // [B,H,L,64], pre-scaled 1/8
  u16* kws = (u16*)alloc((size_t)8192*64*2*8);   // [B,H,L,64]
  u16* vt  = (u16*)alloc((size_t)8192*64*2*8);   // [B,H,64,L]
  float* ctxb = (float*)alloc((size_t)8192*512*4); // [B,L,512] fp32
  u16* relk80 = (u16*)alloc((size_t)80*64*2);
  u16* relvT  = (u16*)alloc((size_t)64*96*2);
  if (off > ws_size) return;

  dim3 gt(16,16);
  k_cvt_wt<<<gt, 256, 0, stream>>>(Wk, WkT);
  k_cvt_wt<<<gt, 256, 0, stream>>>(Wq, WqT);
  k_cvt_wt<<<gt, 256, 0, stream>>>(Wv, WvT);
  k_cvt_wt<<<gt, 256, 0, stream>>>(Wo, WoT);
  k_prep_rel<<<44, 256, 0, stream>>>(rek, rev, relk80, relvT);

  dim3 gg(8, 64);
  k_gemm<<<gg, 256, 0, stream>>>(query, WqT, bq, (void*)qws, 1, 0.125f);
  k_gemm<<<gg, 256, 0, stream>>>(key,   WkT, bk, (void*)kws, 1, 1.0f);
  k_gemm<<<gg, 256, 0, stream>>>(value, WvT, bv, (void*)vt,  2, 1.0f);

  k_attn<<<512, 256, 0, stream>>>(qws, kws, vt, relk80, relvT, te, relm, relw, maskp, ctxb);

  k_gemm<<<gg, 256, 0, stream>>>(ctxb, WoT, bo, d_out, 0, 1.0f);
}